// Round 11
// baseline (103.523 us; speedup 1.0000x reference)
//
#include <hip/hip_runtime.h>
#include <math.h>

#define B_ 8
#define T_ 2048
#define C_ 1024
#define H_ 128

#define TQA 32           // q rows per attention block (one 32-row tile)

#define GM 64            // gemm M-tile
#define GN 128           // gemm N-tile
#define GK 64            // gemm K-tile

typedef __attribute__((ext_vector_type(8))) short s16x8;
typedef __attribute__((ext_vector_type(4))) float f32x4;
typedef __attribute__((ext_vector_type(8))) _Float16 f16x8;
typedef __attribute__((ext_vector_type(4))) _Float16 f16x4;

// ---------------------------------------------------------------------------
// Kernel 0: W prep — transpose W[k][h] (q,k,v) into Wtf[n][k] fp16.
// ---------------------------------------------------------------------------
__global__ __launch_bounds__(256) void wprep(
    const float* __restrict__ Wq, const float* __restrict__ Wk,
    const float* __restrict__ Wv, _Float16* __restrict__ Wtf)
{
    const int n   = blockIdx.x;           // 0..383
    const int mat = n >> 7;
    const int h   = n & 127;
    const float* W = (mat == 0) ? Wq : (mat == 1) ? Wk : Wv;
    for (int k = threadIdx.x; k < C_; k += 256)
        Wtf[(size_t)n * C_ + k] = (_Float16)W[(size_t)k * H_ + h];
}

// ---------------------------------------------------------------------------
// Kernel 1: 2-term fp16 MFMA GEMM (unchanged from round 8).
// ---------------------------------------------------------------------------
__global__ __launch_bounds__(256, 3) void gemm_proj(
    const float* __restrict__ x,
    const _Float16* __restrict__ Wtf,
    const float* __restrict__ bq, const float* __restrict__ bk,
    const float* __restrict__ bv,
    _Float16* __restrict__ qg, _Float16* __restrict__ kg,
    _Float16* __restrict__ vg)
{
    __shared__ _Float16 Ah[GM * GK];      // 8 KB
    __shared__ _Float16 Al[GM * GK];      // 8 KB
    __shared__ _Float16 Bf[GN * GK];      // 16 KB

    const int tid  = threadIdx.x;
    const int my   = blockIdx.y;
    const long m0  = (long)blockIdx.x * GM;
    const int lane = tid & 63;
    const int w    = tid >> 6;
    const int wr   = w >> 1, wc = w & 1;
    const int lg   = lane >> 4, lc = lane & 15;

    float4 xr[4];

    #define LOAD_X(k0)                                                        \
        _Pragma("unroll")                                                     \
        for (int it = 0; it < 4; ++it) {                                      \
            const int i  = tid + it * 256;                                    \
            const int r  = i >> 4;                                            \
            const int k4 = i & 15;                                            \
            xr[it] = *(const float4*)&x[(m0 + r) * C_ + (k0) + k4 * 4];       \
        }

    #define STORE_LDS(k0)                                                     \
        _Pragma("unroll")                                                     \
        for (int it = 0; it < 4; ++it) {                                      \
            const int i  = tid + it * 256;                                    \
            const int r  = i >> 4;                                            \
            const int k4 = i & 15;                                            \
            f16x4 hi4, lo4;                                                   \
            _Pragma("unroll")                                                 \
            for (int j = 0; j < 4; ++j) {                                     \
                const float f = ((const float*)&xr[it])[j];                   \
                const _Float16 h16 = (_Float16)f;                             \
                hi4[j] = h16;                                                 \
                lo4[j] = (_Float16)(f - (float)h16);                          \
            }                                                                 \
            const int off = r * 64 + (((k4 >> 1) ^ (r & 7)) << 3)             \
                          + ((k4 & 1) << 2);                                  \
            *(f16x4*)&Ah[off] = hi4;                                          \
            *(f16x4*)&Al[off] = lo4;                                          \
        }                                                                     \
        _Pragma("unroll")                                                     \
        for (int it = 0; it < 4; ++it) {                                      \
            const int i = tid + it * 256;                                     \
            const int r = i >> 3;                                             \
            const int s = i & 7;                                              \
            const size_t g = (size_t)(my * GN + r) * C_ + (k0) + s * 8;       \
            const int off = r * 64 + ((s ^ (r & 7)) << 3);                    \
            *(f16x8*)&Bf[off] = *(const f16x8*)&Wtf[g];                       \
        }

    f32x4 acc[2][4];
    #pragma unroll
    for (int m = 0; m < 2; ++m)
        #pragma unroll
        for (int n = 0; n < 4; ++n) acc[m][n] = (f32x4){0.f, 0.f, 0.f, 0.f};

    LOAD_X(0);
    STORE_LDS(0);
    __syncthreads();

    for (int kt = 0; kt < C_ / GK; ++kt) {
        if (kt < C_ / GK - 1) LOAD_X((kt + 1) * GK);

        #pragma unroll
        for (int kc = 0; kc < 2; ++kc) {
            f16x8 afh[2], afl[2], bf[4];
            #pragma unroll
            for (int m = 0; m < 2; ++m) {
                const int r = wr * 32 + m * 16 + lc;
                const int off = r * 64 + ((((kc << 2) + lg) ^ (r & 7)) << 3);
                afh[m] = *(const f16x8*)&Ah[off];
                afl[m] = *(const f16x8*)&Al[off];
            }
            #pragma unroll
            for (int n = 0; n < 4; ++n) {
                const int r = wc * 64 + n * 16 + lc;
                const int off = r * 64 + ((((kc << 2) + lg) ^ (r & 7)) << 3);
                bf[n] = *(const f16x8*)&Bf[off];
            }
            #pragma unroll
            for (int m = 0; m < 2; ++m)
                #pragma unroll
                for (int n = 0; n < 4; ++n) {
                    acc[m][n] = __builtin_amdgcn_mfma_f32_16x16x32_f16(afh[m], bf[n], acc[m][n], 0, 0, 0);
                    acc[m][n] = __builtin_amdgcn_mfma_f32_16x16x32_f16(afl[m], bf[n], acc[m][n], 0, 0, 0);
                }
        }
        __syncthreads();
        if (kt < C_ / GK - 1) {
            STORE_LDS((kt + 1) * GK);
            __syncthreads();
        }
    }

    const float* bias = (my == 0) ? bq : (my == 1) ? bk : bv;
    _Float16* og = (my == 0) ? qg : (my == 1) ? kg : vg;

    #pragma unroll
    for (int n = 0; n < 4; ++n) {
        const int h = wc * 64 + n * 16 + lc;
        const float bv_ = bias[h];
        #pragma unroll
        for (int m = 0; m < 2; ++m) {
            #pragma unroll
            for (int rr = 0; rr < 4; ++rr) {
                const long row = m0 + wr * 32 + m * 16 + lg * 4 + rr;
                og[(size_t)row * H_ + h] = (_Float16)(acc[m][n][rr] + bv_);
            }
        }
    }
}

// ---------------------------------------------------------------------------
// Kernel 1b: vtrans — vg [B][T][H] -> vtg [B][H][T] (fp16 bits via short).
// ---------------------------------------------------------------------------
__global__ __launch_bounds__(256) void vtrans(
    const short* __restrict__ vh, short* __restrict__ vtg)
{
    __shared__ short tbuf[64][72];
    const int b  = blockIdx.z;
    const int t0 = blockIdx.x * 64;
    const int h0 = blockIdx.y * 64;
    const int tid = threadIdx.x;
    const size_t bo  = (size_t)b * T_ * H_;
    const size_t vbo = (size_t)b * H_ * T_;

    #pragma unroll
    for (int it = 0; it < 2; ++it) {
        const int u = tid + it * 256;
        const int r = u >> 3, c8 = u & 7;
        *(s16x8*)&tbuf[r][c8 * 8] =
            *(const s16x8*)&vh[bo + (size_t)(t0 + r) * H_ + h0 + c8 * 8];
    }
    __syncthreads();
    #pragma unroll
    for (int it = 0; it < 2; ++it) {
        const int u = tid + it * 256;
        const int t8 = u >> 6, hr = u & 63;
        s16x8 v;
        #pragma unroll
        for (int j = 0; j < 8; ++j) v[j] = tbuf[t8 * 8 + j][hr];
        *(s16x8*)&vtg[vbo + (size_t)(h0 + hr) * T_ + t0 + t8 * 8] = v;
    }
}

// ---------------------------------------------------------------------------
// Kernel 2: causal flash attention v7 — NO LDS staging, no main-loop barrier.
// 4 waves/block; wave w owns ALL 32 q-rows x key tiles kt == w (mod 4).
// K/V fragments loaded global->register (L2-resident, cacheline-clean):
//   K  b128: lanes lg=0..3 read 64B contiguous per key row.
//   V^T b64: lanes lg=0..3 read 32B contiguous per h row.
// K reg-double-buffered (prefetch after QK); V issued at round top.
// 4-way (m,l,O) merge in LDS at epilogue; all waves share the merge.
// ---------------------------------------------------------------------------
__global__ __launch_bounds__(256, 2) void attn_v7(
    const _Float16* __restrict__ qg, const _Float16* __restrict__ kg,
    const _Float16* __restrict__ vtg, float* __restrict__ out)
{
    __shared__ float Ol[4][32][132];      // 67.6 KB
    __shared__ float Ml[4][32][2];        // 1 KB

    const int tid  = threadIdx.x;
    const int lane = tid & 63;
    const int w    = tid >> 6;            // key-tile phase (mod 4)
    const int lg   = lane >> 4;
    const int lc   = lane & 15;
    const int wg   = blockIdx.x;
    const int rank = wg >> 3;
    const int tile = (rank < 32) ? (63 - rank) : (rank - 32);
    const int b    = wg & 7;
    const int t0   = tile * TQA;

    const size_t bo  = (size_t)b * T_ * H_;
    const size_t vbo = (size_t)b * H_ * T_;
    const int nt = tile + 1;              // 32-key tiles

    // ---- Q fragments: 32 rows = 2 halves; B-operand of swapped QK ----
    f16x8 qf[2][4];
    #pragma unroll
    for (int qh = 0; qh < 2; ++qh)
        #pragma unroll
        for (int kc = 0; kc < 4; ++kc)
            qf[qh][kc] = *(const f16x8*)&qg[bo
                + (size_t)(t0 + qh * 16 + lc) * H_ + kc * 32 + lg * 8];

    f32x4 Oacc[2][8];
    #pragma unroll
    for (int qh = 0; qh < 2; ++qh)
        #pragma unroll
        for (int ht = 0; ht < 8; ++ht) Oacc[qh][ht] = (f32x4){0.f,0.f,0.f,0.f};
    float m_run[2] = {-INFINITY, -INFINITY};
    float l_run[2] = {0.f, 0.f};

    f16x8 ka0[8], ka1[8];                 // [kc*2+ct], double-buffered

    #define LOADK(dst, kt_)                                                   \
        _Pragma("unroll")                                                     \
        for (int kc = 0; kc < 4; ++kc)                                        \
            _Pragma("unroll")                                                 \
            for (int ct = 0; ct < 2; ++ct)                                    \
                dst[kc * 2 + ct] = *(const f16x8*)&kg[bo                      \
                    + (size_t)((kt_) * 32 + ct * 16 + lc) * H_                \
                    + kc * 32 + lg * 8];

    #define ROUND(kcur, knxt)                                                 \
    {                                                                         \
        /* V fragments for this tile (issued first, used after softmax) */    \
        f16x4 vb[16];                                                         \
        _Pragma("unroll")                                                     \
        for (int ct = 0; ct < 2; ++ct)                                        \
            _Pragma("unroll")                                                 \
            for (int ht = 0; ht < 8; ++ht)                                    \
                vb[ct * 8 + ht] = *(const f16x4*)&vtg[vbo                     \
                    + (size_t)(ht * 16 + lc) * T_ + kt * 32 + ct * 16 + lg * 4]; \
        /* S^T = K @ Q^T */                                                   \
        f32x4 sfr[2][2];                                                      \
        _Pragma("unroll")                                                     \
        for (int qh = 0; qh < 2; ++qh)                                        \
            _Pragma("unroll")                                                 \
            for (int ct = 0; ct < 2; ++ct)                                    \
                sfr[qh][ct] = (f32x4){0.f, 0.f, 0.f, 0.f};                    \
        _Pragma("unroll")                                                     \
        for (int kc = 0; kc < 4; ++kc)                                        \
            _Pragma("unroll")                                                 \
            for (int ct = 0; ct < 2; ++ct)                                    \
                _Pragma("unroll")                                             \
                for (int qh = 0; qh < 2; ++qh)                                \
                    sfr[qh][ct] = __builtin_amdgcn_mfma_f32_16x16x32_f16(     \
                        kcur[kc * 2 + ct], qf[qh][kc], sfr[qh][ct], 0, 0, 0); \
        /* prefetch next K tile while softmax/PV run */                       \
        if (ktn < nt) { LOADK(knxt, ktn); }                                   \
        /* causal mask: only the diagonal tile */                             \
        if (kt == tile) {                                                     \
            _Pragma("unroll")                                                 \
            for (int qh = 0; qh < 2; ++qh)                                    \
                _Pragma("unroll")                                             \
                for (int ct = 0; ct < 2; ++ct)                                \
                    _Pragma("unroll")                                         \
                    for (int rr = 0; rr < 4; ++rr)                            \
                        if (ct * 16 + lg * 4 + rr > qh * 16 + lc)             \
                            sfr[qh][ct][rr] = -INFINITY;                      \
        }                                                                     \
        /* softmax: lane-local + 2 shfls per q-half */                        \
        float pmax[2];                                                        \
        _Pragma("unroll")                                                     \
        for (int qh = 0; qh < 2; ++qh) {                                      \
            float px = sfr[qh][0][0];                                         \
            _Pragma("unroll")                                                 \
            for (int ct = 0; ct < 2; ++ct)                                    \
                _Pragma("unroll")                                             \
                for (int rr = 0; rr < 4; ++rr)                                \
                    px = fmaxf(px, sfr[qh][ct][rr]);                          \
            px = fmaxf(px, __shfl_xor(px, 16, 64));                           \
            px = fmaxf(px, __shfl_xor(px, 32, 64));                           \
            pmax[qh] = px;                                                    \
        }                                                                     \
        if (__any(pmax[0] > m_run[0] || pmax[1] > m_run[1])) {                \
            _Pragma("unroll")                                                 \
            for (int qh = 0; qh < 2; ++qh) {                                  \
                const float mnew = fmaxf(m_run[qh], pmax[qh]);                \
                const float sc = __expf(m_run[qh] - mnew);                    \
                m_run[qh] = mnew;                                             \
                l_run[qh] *= sc;                                              \
                float scq[4];                                                 \
                _Pragma("unroll")                                             \
                for (int rr = 0; rr < 4; ++rr)                                \
                    scq[rr] = __shfl(sc, lg * 4 + rr, 64);                    \
                _Pragma("unroll")                                             \
                for (int ht = 0; ht < 8; ++ht)                                \
                    _Pragma("unroll")                                         \
                    for (int rr = 0; rr < 4; ++rr)                            \
                        Oacc[qh][ht][rr] *= scq[rr];                          \
            }                                                                 \
        }                                                                     \
        /* exp + in-lane fp16 pack (P in registers) */                        \
        f16x4 pk[2][2];                                                       \
        _Pragma("unroll")                                                     \
        for (int qh = 0; qh < 2; ++qh) {                                      \
            float lsum = 0.f;                                                 \
            _Pragma("unroll")                                                 \
            for (int ct = 0; ct < 2; ++ct)                                    \
                _Pragma("unroll")                                             \
                for (int rr = 0; rr < 4; ++rr) {                              \
                    const float p = __expf(sfr[qh][ct][rr] - m_run[qh]);      \
                    lsum += p;                                                \
                    pk[qh][ct][rr] = (_Float16)p;                             \
                }                                                             \
            l_run[qh] += lsum;                                                \
        }                                                                     \
        /* PV: K=16 MFMAs, V fragments reused across both q-halves */         \
        _Pragma("unroll")                                                     \
        for (int ht = 0; ht < 8; ++ht)                                        \
            _Pragma("unroll")                                                 \
            for (int ct = 0; ct < 2; ++ct)                                    \
                _Pragma("unroll")                                             \
                for (int qh = 0; qh < 2; ++qh)                                \
                    Oacc[qh][ht] = __builtin_amdgcn_mfma_f32_16x16x16f16(     \
                        pk[qh][ct], vb[ct * 8 + ht], Oacc[qh][ht], 0, 0, 0);  \
    }

    int kt = w;
    if (kt < nt) {
        LOADK(ka0, kt);
        int ktn;
        while (true) {
            ktn = kt + 4;
            ROUND(ka0, ka1);
            kt = ktn;
            if (kt >= nt) break;
            ktn = kt + 4;
            ROUND(ka1, ka0);
            kt = ktn;
            if (kt >= nt) break;
        }
    }

    // ---- finish lane-partial l ----
    #pragma unroll
    for (int qh = 0; qh < 2; ++qh) {
        l_run[qh] += __shfl_xor(l_run[qh], 16, 64);
        l_run[qh] += __shfl_xor(l_run[qh], 32, 64);
    }

    // ---- publish all waves' (O, m, l) ----
    #pragma unroll
    for (int qh = 0; qh < 2; ++qh) {
        #pragma unroll
        for (int ht = 0; ht < 8; ++ht)
            #pragma unroll
            for (int rr = 0; rr < 4; ++rr)
                Ol[w][qh * 16 + lg * 4 + rr][ht * 16 + lc] = Oacc[qh][ht][rr];
        if (lg == 0) {
            Ml[w][qh * 16 + lc][0] = m_run[qh];
            Ml[w][qh * 16 + lc][1] = l_run[qh];
        }
    }
    __syncthreads();

    // ---- 4-way merge; wave w writes h-columns ht = 2w, 2w+1 ----
    float fq[2][4][4];                    // [qh][src wave][rr]
    #pragma unroll
    for (int qh = 0; qh < 2; ++qh) {
        float mw[4], lw[4];
        #pragma unroll
        for (int s = 0; s < 4; ++s) {
            mw[s] = Ml[s][qh * 16 + lc][0];
            lw[s] = Ml[s][qh * 16 + lc][1];
        }
        const float M = fmaxf(fmaxf(mw[0], mw[1]), fmaxf(mw[2], mw[3]));
        float f[4], L = 0.f;
        #pragma unroll
        for (int s = 0; s < 4; ++s) { f[s] = __expf(mw[s] - M); L += f[s] * lw[s]; }
        const float inv = 1.f / L;
        #pragma unroll
        for (int s = 0; s < 4; ++s) {
            const float fs = f[s] * inv;
            #pragma unroll
            for (int rr = 0; rr < 4; ++rr)
                fq[qh][s][rr] = __shfl(fs, lg * 4 + rr, 64);
        }
    }
    #pragma unroll
    for (int qh = 0; qh < 2; ++qh)
        #pragma unroll
        for (int ho = 0; ho < 2; ++ho) {
            const int ht = w * 2 + ho;
            #pragma unroll
            for (int rr = 0; rr < 4; ++rr) {
                float val = 0.f;
                #pragma unroll
                for (int s = 0; s < 4; ++s)
                    val += fq[qh][s][rr] * Ol[s][qh * 16 + lg * 4 + rr][ht * 16 + lc];
                out[bo + (size_t)(t0 + qh * 16 + lg * 4 + rr) * H_ + ht * 16 + lc] = val;
            }
        }
}

// ---------------------------------------------------------------------------
extern "C" void kernel_launch(void* const* d_in, const int* in_sizes, int n_in,
                              void* d_out, int out_size, void* d_ws, size_t ws_size,
                              hipStream_t stream)
{
    const float* x  = (const float*)d_in[0];
    const float* Wq = (const float*)d_in[1];
    const float* bq = (const float*)d_in[2];
    const float* Wk = (const float*)d_in[3];
    const float* bk = (const float*)d_in[4];
    const float* Wv = (const float*)d_in[5];
    const float* bv = (const float*)d_in[6];
    float* out = (float*)d_out;

    const size_t SZ = (size_t)B_ * T_ * H_;     // 2M elems
    _Float16* qg  = (_Float16*)d_ws;
    _Float16* kg  = qg + SZ;
    _Float16* vg  = kg + SZ;
    _Float16* vtg = vg + SZ;                     // [B][H][T]
    _Float16* Wtf = vtg + SZ;                    // [384][1024]

    wprep<<<dim3(384), dim3(256), 0, stream>>>(Wq, Wk, Wv, Wtf);
    gemm_proj<<<dim3(B_ * T_ / GM, 3), dim3(256), 0, stream>>>(
        x, Wtf, bq, bk, bv, qg, kg, vg);
    vtrans<<<dim3(T_ / 64, H_ / 64, B_), dim3(256), 0, stream>>>(
        (const short*)vg, (short*)vtg);
    attn_v7<<<dim3(512), dim3(256), 0, stream>>>(qg, kg, vtg, out);
}

// Round 12
// 97.056 us; speedup vs baseline: 1.0666x; 1.0666x over previous
//
#include <hip/hip_runtime.h>
#include <math.h>

#define B_ 8
#define T_ 2048
#define C_ 1024
#define H_ 128

#define TQA 32           // q rows per attention block (2 row-groups x 16)

#define GM 64            // gemm M-tile
#define GN 128           // gemm N-tile
#define GK 64            // gemm K-tile

typedef __attribute__((ext_vector_type(8))) short s16x8;
typedef __attribute__((ext_vector_type(4))) float f32x4;
typedef __attribute__((ext_vector_type(8))) _Float16 f16x8;
typedef __attribute__((ext_vector_type(4))) _Float16 f16x4;

// ---------------------------------------------------------------------------
// Kernel 0: W prep — transpose W[k][h] (q,k,v) into Wtf[n][k] fp16.
// ---------------------------------------------------------------------------
__global__ __launch_bounds__(256) void wprep(
    const float* __restrict__ Wq, const float* __restrict__ Wk,
    const float* __restrict__ Wv, _Float16* __restrict__ Wtf)
{
    const int n   = blockIdx.x;           // 0..383
    const int mat = n >> 7;
    const int h   = n & 127;
    const float* W = (mat == 0) ? Wq : (mat == 1) ? Wk : Wv;
    for (int k = threadIdx.x; k < C_; k += 256)
        Wtf[(size_t)n * C_ + k] = (_Float16)W[(size_t)k * H_ + h];
}

// ---------------------------------------------------------------------------
// Kernel 1: 2-term fp16 MFMA GEMM (unchanged from round 8).
// ---------------------------------------------------------------------------
__global__ __launch_bounds__(256, 3) void gemm_proj(
    const float* __restrict__ x,
    const _Float16* __restrict__ Wtf,
    const float* __restrict__ bq, const float* __restrict__ bk,
    const float* __restrict__ bv,
    _Float16* __restrict__ qg, _Float16* __restrict__ kg,
    _Float16* __restrict__ vg)
{
    __shared__ _Float16 Ah[GM * GK];      // 8 KB
    __shared__ _Float16 Al[GM * GK];      // 8 KB
    __shared__ _Float16 Bf[GN * GK];      // 16 KB

    const int tid  = threadIdx.x;
    const int my   = blockIdx.y;
    const long m0  = (long)blockIdx.x * GM;
    const int lane = tid & 63;
    const int w    = tid >> 6;
    const int wr   = w >> 1, wc = w & 1;
    const int lg   = lane >> 4, lc = lane & 15;

    float4 xr[4];

    #define LOAD_X(k0)                                                        \
        _Pragma("unroll")                                                     \
        for (int it = 0; it < 4; ++it) {                                      \
            const int i  = tid + it * 256;                                    \
            const int r  = i >> 4;                                            \
            const int k4 = i & 15;                                            \
            xr[it] = *(const float4*)&x[(m0 + r) * C_ + (k0) + k4 * 4];       \
        }

    #define STORE_LDS(k0)                                                     \
        _Pragma("unroll")                                                     \
        for (int it = 0; it < 4; ++it) {                                      \
            const int i  = tid + it * 256;                                    \
            const int r  = i >> 4;                                            \
            const int k4 = i & 15;                                            \
            f16x4 hi4, lo4;                                                   \
            _Pragma("unroll")                                                 \
            for (int j = 0; j < 4; ++j) {                                     \
                const float f = ((const float*)&xr[it])[j];                   \
                const _Float16 h16 = (_Float16)f;                             \
                hi4[j] = h16;                                                 \
                lo4[j] = (_Float16)(f - (float)h16);                          \
            }                                                                 \
            const int off = r * 64 + (((k4 >> 1) ^ (r & 7)) << 3)             \
                          + ((k4 & 1) << 2);                                  \
            *(f16x4*)&Ah[off] = hi4;                                          \
            *(f16x4*)&Al[off] = lo4;                                          \
        }                                                                     \
        _Pragma("unroll")                                                     \
        for (int it = 0; it < 4; ++it) {                                      \
            const int i = tid + it * 256;                                     \
            const int r = i >> 3;                                             \
            const int s = i & 7;                                              \
            const size_t g = (size_t)(my * GN + r) * C_ + (k0) + s * 8;       \
            const int off = r * 64 + ((s ^ (r & 7)) << 3);                    \
            *(f16x8*)&Bf[off] = *(const f16x8*)&Wtf[g];                       \
        }

    f32x4 acc[2][4];
    #pragma unroll
    for (int m = 0; m < 2; ++m)
        #pragma unroll
        for (int n = 0; n < 4; ++n) acc[m][n] = (f32x4){0.f, 0.f, 0.f, 0.f};

    LOAD_X(0);
    STORE_LDS(0);
    __syncthreads();

    for (int kt = 0; kt < C_ / GK; ++kt) {
        if (kt < C_ / GK - 1) LOAD_X((kt + 1) * GK);

        #pragma unroll
        for (int kc = 0; kc < 2; ++kc) {
            f16x8 afh[2], afl[2], bf[4];
            #pragma unroll
            for (int m = 0; m < 2; ++m) {
                const int r = wr * 32 + m * 16 + lc;
                const int off = r * 64 + ((((kc << 2) + lg) ^ (r & 7)) << 3);
                afh[m] = *(const f16x8*)&Ah[off];
                afl[m] = *(const f16x8*)&Al[off];
            }
            #pragma unroll
            for (int n = 0; n < 4; ++n) {
                const int r = wc * 64 + n * 16 + lc;
                const int off = r * 64 + ((((kc << 2) + lg) ^ (r & 7)) << 3);
                bf[n] = *(const f16x8*)&Bf[off];
            }
            #pragma unroll
            for (int m = 0; m < 2; ++m)
                #pragma unroll
                for (int n = 0; n < 4; ++n) {
                    acc[m][n] = __builtin_amdgcn_mfma_f32_16x16x32_f16(afh[m], bf[n], acc[m][n], 0, 0, 0);
                    acc[m][n] = __builtin_amdgcn_mfma_f32_16x16x32_f16(afl[m], bf[n], acc[m][n], 0, 0, 0);
                }
        }
        __syncthreads();
        if (kt < C_ / GK - 1) {
            STORE_LDS((kt + 1) * GK);
            __syncthreads();
        }
    }

    const float* bias = (my == 0) ? bq : (my == 1) ? bk : bv;
    _Float16* og = (my == 0) ? qg : (my == 1) ? kg : vg;

    #pragma unroll
    for (int n = 0; n < 4; ++n) {
        const int h = wc * 64 + n * 16 + lc;
        const float bv_ = bias[h];
        #pragma unroll
        for (int m = 0; m < 2; ++m) {
            #pragma unroll
            for (int rr = 0; rr < 4; ++rr) {
                const long row = m0 + wr * 32 + m * 16 + lg * 4 + rr;
                og[(size_t)row * H_ + h] = (_Float16)(acc[m][n][rr] + bv_);
            }
        }
    }
}

// ---------------------------------------------------------------------------
// Kernel 1b: vtrans — vg [B][T][H] -> vtg [B][H][T] (fp16 bits via short).
// ---------------------------------------------------------------------------
__global__ __launch_bounds__(256) void vtrans(
    const short* __restrict__ vh, short* __restrict__ vtg)
{
    __shared__ short tbuf[64][72];
    const int b  = blockIdx.z;
    const int t0 = blockIdx.x * 64;
    const int h0 = blockIdx.y * 64;
    const int tid = threadIdx.x;
    const size_t bo  = (size_t)b * T_ * H_;
    const size_t vbo = (size_t)b * H_ * T_;

    #pragma unroll
    for (int it = 0; it < 2; ++it) {
        const int u = tid + it * 256;
        const int r = u >> 3, c8 = u & 7;
        *(s16x8*)&tbuf[r][c8 * 8] =
            *(const s16x8*)&vh[bo + (size_t)(t0 + r) * H_ + h0 + c8 * 8];
    }
    __syncthreads();
    #pragma unroll
    for (int it = 0; it < 2; ++it) {
        const int u = tid + it * 256;
        const int t8 = u >> 6, hr = u & 63;
        s16x8 v;
        #pragma unroll
        for (int j = 0; j < 8; ++j) v[j] = tbuf[t8 * 8 + j][hr];
        *(s16x8*)&vtg[vbo + (size_t)(h0 + hr) * T_ + t0 + t8 * 8] = v;
    }
}

// ---------------------------------------------------------------------------
// Kernel 2: causal flash attention v8 — v5 staged skeleton + in-register P,
// 32-key rounds, LDS 32 KB -> 4 blocks/CU (16 waves, 2x v5 occupancy).
// 4 waves: rg=w>>1 (16 q rows), kp=w&1 (16-key half of each 32-key tile).
// Per wave round: 4 QKT MFMA (2 indep chains) + softmax(4) + 8 indep PV
// K=16 MFMA. m_run init -1e30 (not -inf): fully-masked half-tiles stay
// NaN-free (exp(-inf - (-1e30)) = 0).
// ---------------------------------------------------------------------------
__global__ __launch_bounds__(256, 4) void attn_v8(
    const _Float16* __restrict__ qg, const _Float16* __restrict__ kg,
    const _Float16* __restrict__ vtg, float* __restrict__ out)
{
    __shared__ __align__(16) char smem[32768];
    _Float16* Kbuf = (_Float16*)smem;              // [2][32*128]  16 KB
    _Float16* Vbuf = (_Float16*)(smem + 16384);    // [2][128*32]  16 KB
    float* Ocmb = (float*)smem;                    // [32][132] (aliased)
    float* Mcmb = (float*)(smem + 16896);          // [32][2]   (aliased)

    const int tid  = threadIdx.x;
    const int lane = tid & 63;
    const int w    = tid >> 6;
    const int rg   = w >> 1;
    const int kp   = w & 1;
    const int lg   = lane >> 4;
    const int lc   = lane & 15;
    const int wg   = blockIdx.x;
    const int rank = wg >> 3;
    const int tile = (rank < 32) ? (63 - rank) : (rank - 32);
    const int b    = wg & 7;
    const int t0   = tile * TQA;

    const size_t bo  = (size_t)b * T_ * H_;
    const size_t vbo = (size_t)b * H_ * T_;

    // Q fragment (B-operand of swapped QK): lane lc holds q-row t0+rg*16+lc
    f16x8 qf[4];
    {
        const size_t qbase = bo + (size_t)(t0 + rg * 16 + lc) * H_;
        #pragma unroll
        for (int kc = 0; kc < 4; ++kc)
            qf[kc] = *(const f16x8*)(qg + qbase + kc * 32 + lg * 8);
    }

    f32x4 Oacc[8];
    #pragma unroll
    for (int ht = 0; ht < 8; ++ht) Oacc[ht] = (f32x4){0.f, 0.f, 0.f, 0.f};
    float m_run = -1e30f;                 // finite sentinel (NaN-free masking)
    float l_run = 0.f;                    // lane-partial

    const int R = tile + 1;               // one 32-key tile per round

    f16x8 pf[4];                          // staged 16 KB / 256 threads

    // chunk c = tid + it*256 in [0,1024): c<512 -> K (key=c>>4 in 0..31,
    // slot=c&15, global h-group = slot^(key&7)); else V (hh=(c-512)>>2,
    // slot=c&3, global key-group = slot^((hh>>1)&3)).
    #define ISSUE_ST(rs0_)                                                    \
        _Pragma("unroll")                                                     \
        for (int it = 0; it < 4; ++it) {                                      \
            const int c = tid + it * 256;                                     \
            if (c < 512) {                                                    \
                const int key = c >> 4, slot = c & 15;                        \
                const int hc = slot ^ (key & 7);                              \
                pf[it] = *(const f16x8*)(kg + bo                              \
                          + (size_t)((rs0_) + key) * H_ + hc * 8);            \
            } else {                                                          \
                const int cc = c - 512;                                       \
                const int hh = cc >> 2, slot = cc & 3;                        \
                const int k8 = slot ^ ((hh >> 1) & 3);                        \
                pf[it] = *(const f16x8*)(vtg + vbo + (size_t)hh * T_          \
                          + (rs0_) + k8 * 8);                                 \
            }                                                                 \
        }

    #define WRITE_ST(bf_)                                                    \
        _Pragma("unroll")                                                     \
        for (int it = 0; it < 4; ++it) {                                      \
            const int c = tid + it * 256;                                     \
            if (c < 512) {                                                    \
                const int key = c >> 4, slot = c & 15;                        \
                *(f16x8*)&Kbuf[(bf_) * 4096 + key * 128 + slot * 8] = pf[it]; \
            } else {                                                          \
                const int cc = c - 512;                                       \
                const int hh = cc >> 2, slot = cc & 3;                        \
                *(f16x8*)&Vbuf[(bf_) * 4096 + hh * 32 + slot * 8] = pf[it];   \
            }                                                                 \
        }

    ISSUE_ST(0);

    for (int r = 0; r < R; ++r) {
        const int bf = r & 1;
        WRITE_ST(bf);                     // waits vmcnt on pf (compiler)
        __syncthreads();                  // buffer bf ready
        if (r + 1 < R) ISSUE_ST((r + 1) * 32);

        // ---- S^T = K_half @ Q^T : keys kp*16+lg*4+rr, qrow = lc ----
        f32x4 sfrA = (f32x4){0.f, 0.f, 0.f, 0.f};
        f32x4 sfrB = (f32x4){0.f, 0.f, 0.f, 0.f};
        #pragma unroll
        for (int kc = 0; kc < 4; ++kc) {
            const int key  = kp * 16 + lc;               // local key row
            const int slot = (kc * 4 + lg) ^ (key & 7);
            const f16x8 ka = *(const f16x8*)&Kbuf[bf * 4096 + key * 128 + slot * 8];
            if (kc < 2)
                sfrA = __builtin_amdgcn_mfma_f32_16x16x32_f16(ka, qf[kc], sfrA, 0, 0, 0);
            else
                sfrB = __builtin_amdgcn_mfma_f32_16x16x32_f16(ka, qf[kc], sfrB, 0, 0, 0);
        }
        f32x4 sfr = sfrA + sfrB;

        // ---- causal mask (diagonal tile only) ----
        if (r == R - 1) {
            const int qrow_g = t0 + rg * 16 + lc;
            #pragma unroll
            for (int rr = 0; rr < 4; ++rr) {
                const int key_g = r * 32 + kp * 16 + lg * 4 + rr;
                if (key_g > qrow_g) sfr[rr] = -INFINITY;
            }
        }

        // ---- softmax: lane-local over 4 regs + 2 shfls ----
        float pmax = fmaxf(fmaxf(sfr[0], sfr[1]), fmaxf(sfr[2], sfr[3]));
        pmax = fmaxf(pmax, __shfl_xor(pmax, 16, 64));
        pmax = fmaxf(pmax, __shfl_xor(pmax, 32, 64));

        if (__any(pmax > m_run)) {
            const float mnew = fmaxf(m_run, pmax);
            const float sc = __expf(m_run - mnew);
            m_run = mnew;
            l_run *= sc;
            float scq[4];
            #pragma unroll
            for (int rr = 0; rr < 4; ++rr)
                scq[rr] = __shfl(sc, lg * 4 + rr, 64);
            #pragma unroll
            for (int ht = 0; ht < 8; ++ht)
                #pragma unroll
                for (int rr = 0; rr < 4; ++rr) Oacc[ht][rr] *= scq[rr];
        }

        // ---- exp + in-lane fp16 pack (P stays in registers) ----
        f16x4 pk;
        float lsum = 0.f;
        #pragma unroll
        for (int rr = 0; rr < 4; ++rr) {
            const float p = __expf(sfr[rr] - m_run);     // masked -> 0
            lsum += p;
            pk[rr] = (_Float16)p;
        }
        l_run += lsum;

        // ---- PV: 8 independent K=16 MFMAs; V^T b64 reads ----
        // stored slot s holds key-group (s ^ ((hh>>1)&3)); need group
        // kp*2 + (lg>>1), sub-offset (lg&1)*4.
        #pragma unroll
        for (int ht = 0; ht < 8; ++ht) {
            const int hh   = ht * 16 + lc;
            const int slot = (kp * 2 + (lg >> 1)) ^ ((hh >> 1) & 3);
            const int addr = bf * 4096 + hh * 32 + slot * 8 + (lg & 1) * 4;
            const f16x4 vb = *(const f16x4*)&Vbuf[addr];
            Oacc[ht] = __builtin_amdgcn_mfma_f32_16x16x16f16(pk, vb, Oacc[ht], 0, 0, 0);
        }
    }

    // ---- finish lane-partial l: sum the 4 lg groups per qrow ----
    l_run += __shfl_xor(l_run, 16, 64);
    l_run += __shfl_xor(l_run, 32, 64);

    __syncthreads();                      // all rounds done before aliasing

    // ---- pair combine: kp=1 publishes, kp=0 merges + writes ----
    if (kp == 1) {
        #pragma unroll
        for (int ht = 0; ht < 8; ++ht)
            #pragma unroll
            for (int rr = 0; rr < 4; ++rr)
                Ocmb[(size_t)(rg * 16 + lg * 4 + rr) * 132 + ht * 16 + lc] =
                    Oacc[ht][rr];
        if (lg == 0) {
            Mcmb[(rg * 16 + lc) * 2]     = m_run;
            Mcmb[(rg * 16 + lc) * 2 + 1] = l_run;
        }
    }
    __syncthreads();
    if (kp == 0) {
        const float m1 = Mcmb[(rg * 16 + lc) * 2];
        const float l1 = Mcmb[(rg * 16 + lc) * 2 + 1];
        const float M  = fmaxf(m_run, m1);
        const float a0 = __expf(m_run - M);
        const float a1 = __expf(m1 - M);
        const float inv = 1.f / (l_run * a0 + l1 * a1);
        const float f0 = a0 * inv, f1 = a1 * inv;
        float f0q[4], f1q[4];
        #pragma unroll
        for (int rr = 0; rr < 4; ++rr) {
            f0q[rr] = __shfl(f0, lg * 4 + rr, 64);
            f1q[rr] = __shfl(f1, lg * 4 + rr, 64);
        }
        float* ob = out + bo + (size_t)(t0 + rg * 16) * H_;
        #pragma unroll
        for (int ht = 0; ht < 8; ++ht)
            #pragma unroll
            for (int rr = 0; rr < 4; ++rr) {
                const float o1 =
                    Ocmb[(size_t)(rg * 16 + lg * 4 + rr) * 132 + ht * 16 + lc];
                ob[(size_t)(lg * 4 + rr) * H_ + ht * 16 + lc] =
                    Oacc[ht][rr] * f0q[rr] + o1 * f1q[rr];
            }
    }
}

// ---------------------------------------------------------------------------
extern "C" void kernel_launch(void* const* d_in, const int* in_sizes, int n_in,
                              void* d_out, int out_size, void* d_ws, size_t ws_size,
                              hipStream_t stream)
{
    const float* x  = (const float*)d_in[0];
    const float* Wq = (const float*)d_in[1];
    const float* bq = (const float*)d_in[2];
    const float* Wk = (const float*)d_in[3];
    const float* bk = (const float*)d_in[4];
    const float* Wv = (const float*)d_in[5];
    const float* bv = (const float*)d_in[6];
    float* out = (float*)d_out;

    const size_t SZ = (size_t)B_ * T_ * H_;     // 2M elems
    _Float16* qg  = (_Float16*)d_ws;
    _Float16* kg  = qg + SZ;
    _Float16* vg  = kg + SZ;
    _Float16* vtg = vg + SZ;                     // [B][H][T]
    _Float16* Wtf = vtg + SZ;                    // [384][1024]

    wprep<<<dim3(384), dim3(256), 0, stream>>>(Wq, Wk, Wv, Wtf);
    gemm_proj<<<dim3(B_ * T_ / GM, 3), dim3(256), 0, stream>>>(
        x, Wtf, bq, bk, bv, qg, kg, vg);
    vtrans<<<dim3(T_ / 64, H_ / 64, B_), dim3(256), 0, stream>>>(
        (const short*)vg, (short*)vtg);
    attn_v8<<<dim3(512), dim3(256), 0, stream>>>(qg, kg, vtg, out);
}